// Round 11
// baseline (92.253 us; speedup 1.0000x reference)
//
#include <hip/hip_runtime.h>

#define NROWS 1000000
#define NB    3907         // ceil(1e6 / 256) mask blocks
#define NT    62500        // 16-row tiles
#define TPB   4            // tiles per wave-batch
#define NBATCH (NT / TPB)  // 15625, exact
#define MLP_BLOCKS 1024    // 256 CUs x 4 blocks (34KB LDS each)

typedef __bf16 bf16x8 __attribute__((ext_vector_type(8)));
typedef float  f32x4  __attribute__((ext_vector_type(4)));

// f32 pair -> packed bf16 (RNE), 1 instr (no builtin on gfx950; T12 recipe)
__device__ __forceinline__ unsigned cvt_pk_bf16(float lo, float hi) {
  unsigned r;
  asm("v_cvt_pk_bf16_f32 %0, %1, %2" : "=v"(r) : "v"(lo), "v"(hi));
  return r;
}

// ---------------------------------------------------------------------------
// Kernel 1: per-256-row-block nonzero counts (3907 sums).
// ---------------------------------------------------------------------------
__global__ __launch_bounds__(256) void count_kernel(
    const int* __restrict__ mask, int* __restrict__ bsum) {
  int tid = threadIdx.x;
  int row = blockIdx.x * 256 + tid;
  int cnt = 0;
  if (row < NROWS) {
    const int4* mp = (const int4*)(mask + (long)row * 8);
    int4 a = mp[0], b = mp[1];
    cnt = (a.x != 0) + (a.y != 0) + (a.z != 0) + (a.w != 0) +
          (b.x != 0) + (b.y != 0) + (b.z != 0) + (b.w != 0);
  }
#pragma unroll
  for (int off = 1; off < 64; off <<= 1) cnt += __shfl_xor(cnt, off);
  __shared__ int ws[4];
  if ((tid & 63) == 0) ws[tid >> 6] = cnt;
  __syncthreads();
  if (tid == 0) bsum[blockIdx.x] = ws[0] + ws[1] + ws[2] + ws[3];
}

// ---------------------------------------------------------------------------
// Kernel 2: exclusive scan of 3907 block sums (single block, coalesced).
// ---------------------------------------------------------------------------
__global__ __launch_bounds__(1024) void scan_kernel(
    const int* __restrict__ bsum, int* __restrict__ boff) {
  __shared__ int lds[1024];
  int t = threadIdx.x;
  int i0 = t * 4;
  int c0 = (i0 + 0 < NB) ? bsum[i0 + 0] : 0;
  int c1 = (i0 + 1 < NB) ? bsum[i0 + 1] : 0;
  int c2 = (i0 + 2 < NB) ? bsum[i0 + 2] : 0;
  int c3 = (i0 + 3 < NB) ? bsum[i0 + 3] : 0;
  int s = c0 + c1 + c2 + c3;
  lds[t] = s;
  __syncthreads();
  for (int off = 1; off < 1024; off <<= 1) {
    int v = lds[t];
    int add = (t >= off) ? lds[t - off] : 0;
    __syncthreads();
    lds[t] = v + add;
    __syncthreads();
  }
  int excl = lds[t] - s;
  if (i0 + 0 < NB) boff[i0 + 0] = excl;
  excl += c0;
  if (i0 + 1 < NB) boff[i0 + 1] = excl;
  excl += c1;
  if (i0 + 2 < NB) boff[i0 + 2] = excl;
  excl += c2;
  if (i0 + 3 < NB) boff[i0 + 3] = excl;
}

// ---------------------------------------------------------------------------
// Kernel 3: per-row info = (scatter_pos << 8) | mask_bits.
// ---------------------------------------------------------------------------
__global__ __launch_bounds__(256) void expand_kernel(
    const int* __restrict__ mask, const int* __restrict__ boff,
    int* __restrict__ rowinfo) {
  int tid = threadIdx.x;
  int row = blockIdx.x * 256 + tid;
  bool valid = row < NROWS;
  unsigned mb = 0;
  int cnt = 0;
  if (valid) {
    const int4* mp = (const int4*)(mask + (long)row * 8);
    int4 a = mp[0], b = mp[1];
    mb = (unsigned)((a.x != 0) | ((a.y != 0) << 1) | ((a.z != 0) << 2) |
                    ((a.w != 0) << 3) | ((b.x != 0) << 4) | ((b.y != 0) << 5) |
                    ((b.z != 0) << 6) | ((b.w != 0) << 7));
    cnt = __popc(mb);
  }
  int incl = cnt;
#pragma unroll
  for (int off = 1; off < 64; off <<= 1) {
    int v = __shfl_up(incl, off);
    if ((tid & 63) >= off) incl += v;
  }
  __shared__ int wsum[4];
  if ((tid & 63) == 63) wsum[tid >> 6] = incl;
  __syncthreads();
  int w = tid >> 6;
  int wo = 0;
  if (w > 0) wo += wsum[0];
  if (w > 1) wo += wsum[1];
  if (w > 2) wo += wsum[2];
  int pos = boff[blockIdx.x] + wo + (incl - cnt);
  if (valid) rowinfo[row] = (pos << 8) | (int)mb;
}

// ---------------------------------------------------------------------------
// Kernel 4: both MLP layers on MFMA + ordered scatter via rowinfo.
// IDENTICAL to round-10 except __launch_bounds__(256, 2): unified VGPR+AGPR
// budget 256/wave (was 128), so MFMA operands stay in VGPRs -> no
// v_accvgpr_read/write shuttling (the hypothesized hidden ~2x VALU load).
// ---------------------------------------------------------------------------
__global__ __launch_bounds__(256, 2) void mlp_kernel(
    const float* __restrict__ x, const float* __restrict__ w0,
    const float* __restrict__ b0, const float* __restrict__ w1,
    const float* __restrict__ b1, const int* __restrict__ rowinfo,
    float* __restrict__ out) {
  __shared__ __bf16 sA[32 * 64 * 8];   // 32 frags x 64 lanes x 8 bf16 = 32 KB
  __shared__ float sB0[512];           // b0 verbatim (frag-sliced reads)

  int tid = threadIdx.x;

  // ---- prologue: stage W0^T fragments (bf16) + b0 ----
#pragma unroll
  for (int i = 0; i < 8; ++i) {
    int fi = i * 256 + tid;          // 0..2047
    int frag = fi >> 6;              // hidden-block 0..31 (label = frag*16+m)
    int lane = fi & 63;
    int d = frag >> 2, qb = frag & 3;
    int q = qb * 16 + (lane & 15);   // within-head hidden index
    int kb = (lane >> 4) * 8;        // k chunk per 16-lane group
    bf16x8 v;
#pragma unroll
    for (int j = 0; j < 8; ++j)
      v[j] = (__bf16)w0[d * 2048 + (kb + j) * 64 + q];
    *(bf16x8*)&sA[fi * 8] = v;
  }
  if (tid < 128) *(float4*)&sB0[tid * 4] = *(const float4*)&b0[tid * 4];
  __syncthreads();

  int l = tid & 63;
  int n = l & 15;          // MFMA col / row-in-tile; also A2 row index m
  int g = l >> 4;          // 16-lane group

  // ---- persistent per-lane w1 fragments (labels c1=2n even / 2n+1 odd) ----
  bf16x8 w1A, w1B;
  bool ownrow = (n < 8);
#pragma unroll
  for (int j = 0; j < 8; ++j) {
    int off = (j >> 2) * 16 + g * 4 + (j & 3);
    w1A[j] = ownrow ? (__bf16)w1[n * 64 + off]      : (__bf16)0.f;
    w1B[j] = ownrow ? (__bf16)w1[n * 64 + 32 + off] : (__bf16)0.f;
  }
  int4 w1Ai = *(int4*)&w1A;
  int4 w1Bi = *(int4*)&w1B;
  f32x4 b1C;
#pragma unroll
  for (int r = 0; r < 4; ++r) b1C[r] = b1[(g * 4 + r) & 7];

  int w = tid >> 6;
  int wv = blockIdx.x * 4 + w;
  const int W = MLP_BLOCKS * 4;

  for (int b = wv; b < NBATCH; b += W) {
    int t0 = b * TPB;

    // ---- x fragments: B[k][n], k-slot (g,j) -> feature g*8+j ----
    bf16x8 xf0, xf1, xf2, xf3;
    {
      const float* xp;
      float4 a, c;
      uint4 ui;
#define LOADX(T, DST)                                              \
      xp = x + (long)((t0 + T) * 16 + n) * 32 + g * 8;             \
      a = *(const float4*)xp; c = *(const float4*)(xp + 4);        \
      ui.x = cvt_pk_bf16(a.x, a.y); ui.y = cvt_pk_bf16(a.z, a.w); \
      ui.z = cvt_pk_bf16(c.x, c.y); ui.w = cvt_pk_bf16(c.z, c.w); \
      DST = *(bf16x8*)&ui;
      LOADX(0, xf0) LOADX(1, xf1) LOADX(2, xf2) LOADX(3, xf3)
#undef LOADX
    }

    f32x4 O0 = b1C, O1 = b1C, O2 = b1C, O3 = b1C;

#pragma unroll 1
    for (int cp = 0; cp < 8; ++cp) {   // head cp; c1 = 2cp (w1A), 2cp+1 (w1B)
      bool own = (n == cp);
      int4 z4 = {0, 0, 0, 0};
      int4 A2ai = own ? w1Ai : z4;     // 4 cndmask each
      int4 A2bi = own ? w1Bi : z4;
      bf16x8 A2a = *(bf16x8*)&A2ai;
      bf16x8 A2b = *(bf16x8*)&A2bi;
      int fb = cp * 4;                 // 4 layer-0 frags this head
      bf16x8 Aw0 = *(const bf16x8*)&sA[(fb + 0) * 512 + l * 8];
      bf16x8 Aw1 = *(const bf16x8*)&sA[(fb + 1) * 512 + l * 8];
      bf16x8 Aw2 = *(const bf16x8*)&sA[(fb + 2) * 512 + l * 8];
      bf16x8 Aw3 = *(const bf16x8*)&sA[(fb + 3) * 512 + l * 8];
      f32x4 C0 = *(const f32x4*)&sB0[(fb + 0) * 16 + g * 4];
      f32x4 C1 = *(const f32x4*)&sB0[(fb + 1) * 16 + g * 4];
      f32x4 C2 = *(const f32x4*)&sB0[(fb + 2) * 16 + g * 4];
      f32x4 C3 = *(const f32x4*)&sB0[(fb + 3) * 16 + g * 4];

#define TILE(XF, OD) {                                                        \
      f32x4 Da = __builtin_amdgcn_mfma_f32_16x16x32_bf16(Aw0, XF, C0, 0,0,0); \
      f32x4 Db = __builtin_amdgcn_mfma_f32_16x16x32_bf16(Aw1, XF, C1, 0,0,0); \
      uint4 bu;                                                               \
      bu.x = cvt_pk_bf16(fmaxf(Da[0], 0.f), fmaxf(Da[1], 0.f));               \
      bu.y = cvt_pk_bf16(fmaxf(Da[2], 0.f), fmaxf(Da[3], 0.f));               \
      bu.z = cvt_pk_bf16(fmaxf(Db[0], 0.f), fmaxf(Db[1], 0.f));               \
      bu.w = cvt_pk_bf16(fmaxf(Db[2], 0.f), fmaxf(Db[3], 0.f));               \
      bf16x8 B2 = *(bf16x8*)&bu;                                              \
      OD = __builtin_amdgcn_mfma_f32_16x16x32_bf16(A2a, B2, OD, 0, 0, 0);     \
      f32x4 Dc = __builtin_amdgcn_mfma_f32_16x16x32_bf16(Aw2, XF, C2, 0,0,0); \
      f32x4 Dd = __builtin_amdgcn_mfma_f32_16x16x32_bf16(Aw3, XF, C3, 0,0,0); \
      bu.x = cvt_pk_bf16(fmaxf(Dc[0], 0.f), fmaxf(Dc[1], 0.f));               \
      bu.y = cvt_pk_bf16(fmaxf(Dc[2], 0.f), fmaxf(Dc[3], 0.f));               \
      bu.z = cvt_pk_bf16(fmaxf(Dd[0], 0.f), fmaxf(Dd[1], 0.f));               \
      bu.w = cvt_pk_bf16(fmaxf(Dd[2], 0.f), fmaxf(Dd[3], 0.f));               \
      bf16x8 B3 = *(bf16x8*)&bu;                                              \
      OD = __builtin_amdgcn_mfma_f32_16x16x32_bf16(A2b, B3, OD, 0, 0, 0); }
      TILE(xf0, O0) TILE(xf1, O1) TILE(xf2, O2) TILE(xf3, O3)
#undef TILE
    }

    // ---- epilogue: lanes g<2 hold out[d=g*4+r][n]; ordered scatter ----
    if (g < 2) {
#define EPI(T, OD) {                                                     \
      int row = (t0 + T) * 16 + n;                                       \
      int info = rowinfo[row];                                           \
      unsigned mb = (unsigned)info & 255u;                               \
      int pos = (int)(((unsigned)info) >> 8) +                           \
                (g ? __popc(mb & 0xFu) : 0);                             \
      unsigned nib = (mb >> (g * 4)) & 0xFu;                             \
      if (nib & 1u) { out[pos] = OD[0]; pos++; }                         \
      if (nib & 2u) { out[pos] = OD[1]; pos++; }                         \
      if (nib & 4u) { out[pos] = OD[2]; pos++; }                         \
      if (nib & 8u) { out[pos] = OD[3]; }                                }
      EPI(0, O0) EPI(1, O1) EPI(2, O2) EPI(3, O3)
#undef EPI
    }
  }
}

extern "C" void kernel_launch(void* const* d_in, const int* in_sizes, int n_in,
                              void* d_out, int out_size, void* d_ws, size_t ws_size,
                              hipStream_t stream) {
  const float* x    = (const float*)d_in[0];
  const int*   mask = (const int*)d_in[1];
  const float* w0   = (const float*)d_in[2];
  const float* b0   = (const float*)d_in[3];
  const float* w1   = (const float*)d_in[4];
  const float* b1   = (const float*)d_in[5];
  float* out = (float*)d_out;

  int* bsum    = (int*)d_ws;            // NB ints
  int* boff    = bsum + NB;             // NB ints
  int* rowinfo = boff + NB;             // NROWS ints (~4 MB)

  count_kernel<<<NB, 256, 0, stream>>>(mask, bsum);
  scan_kernel<<<1, 1024, 0, stream>>>(bsum, boff);
  expand_kernel<<<NB, 256, 0, stream>>>(mask, boff, rowinfo);
  mlp_kernel<<<MLP_BLOCKS, 256, 0, stream>>>(x, w0, b0, w1, b1, rowinfo, out);
}

// Round 12
// 89.471 us; speedup vs baseline: 1.0311x; 1.0311x over previous
//
#include <hip/hip_runtime.h>

#define NROWS 1000000
#define NB    3907         // ceil(1e6 / 256) mask blocks
#define NT    62500        // 16-row tiles
#define TPB   4            // tiles per wave-batch
#define NBATCH (NT / TPB)  // 15625, exact
#define MLP_BLOCKS 768     // 256 CUs x 3 blocks x 8 waves = 24 waves/CU (75%)
#define MLP_THREADS 512

typedef __bf16 bf16x8 __attribute__((ext_vector_type(8)));
typedef float  f32x4  __attribute__((ext_vector_type(4)));

// f32 pair -> packed bf16 (RNE), 1 instr (no builtin on gfx950; T12 recipe)
__device__ __forceinline__ unsigned cvt_pk_bf16(float lo, float hi) {
  unsigned r;
  asm("v_cvt_pk_bf16_f32 %0, %1, %2" : "=v"(r) : "v"(lo), "v"(hi));
  return r;
}

// ---------------------------------------------------------------------------
// Kernel 1: per-256-row-block nonzero counts (3907 sums).
// ---------------------------------------------------------------------------
__global__ __launch_bounds__(256) void count_kernel(
    const int* __restrict__ mask, int* __restrict__ bsum) {
  int tid = threadIdx.x;
  int row = blockIdx.x * 256 + tid;
  int cnt = 0;
  if (row < NROWS) {
    const int4* mp = (const int4*)(mask + (long)row * 8);
    int4 a = mp[0], b = mp[1];
    cnt = (a.x != 0) + (a.y != 0) + (a.z != 0) + (a.w != 0) +
          (b.x != 0) + (b.y != 0) + (b.z != 0) + (b.w != 0);
  }
#pragma unroll
  for (int off = 1; off < 64; off <<= 1) cnt += __shfl_xor(cnt, off);
  __shared__ int ws[4];
  if ((tid & 63) == 0) ws[tid >> 6] = cnt;
  __syncthreads();
  if (tid == 0) bsum[blockIdx.x] = ws[0] + ws[1] + ws[2] + ws[3];
}

// ---------------------------------------------------------------------------
// Kernel 2: exclusive scan of 3907 block sums (single block, coalesced).
// ---------------------------------------------------------------------------
__global__ __launch_bounds__(1024) void scan_kernel(
    const int* __restrict__ bsum, int* __restrict__ boff) {
  __shared__ int lds[1024];
  int t = threadIdx.x;
  int i0 = t * 4;
  int c0 = (i0 + 0 < NB) ? bsum[i0 + 0] : 0;
  int c1 = (i0 + 1 < NB) ? bsum[i0 + 1] : 0;
  int c2 = (i0 + 2 < NB) ? bsum[i0 + 2] : 0;
  int c3 = (i0 + 3 < NB) ? bsum[i0 + 3] : 0;
  int s = c0 + c1 + c2 + c3;
  lds[t] = s;
  __syncthreads();
  for (int off = 1; off < 1024; off <<= 1) {
    int v = lds[t];
    int add = (t >= off) ? lds[t - off] : 0;
    __syncthreads();
    lds[t] = v + add;
    __syncthreads();
  }
  int excl = lds[t] - s;
  if (i0 + 0 < NB) boff[i0 + 0] = excl;
  excl += c0;
  if (i0 + 1 < NB) boff[i0 + 1] = excl;
  excl += c1;
  if (i0 + 2 < NB) boff[i0 + 2] = excl;
  excl += c2;
  if (i0 + 3 < NB) boff[i0 + 3] = excl;
}

// ---------------------------------------------------------------------------
// Kernel 3: per-row info = (scatter_pos << 8) | mask_bits.
// ---------------------------------------------------------------------------
__global__ __launch_bounds__(256) void expand_kernel(
    const int* __restrict__ mask, const int* __restrict__ boff,
    int* __restrict__ rowinfo) {
  int tid = threadIdx.x;
  int row = blockIdx.x * 256 + tid;
  bool valid = row < NROWS;
  unsigned mb = 0;
  int cnt = 0;
  if (valid) {
    const int4* mp = (const int4*)(mask + (long)row * 8);
    int4 a = mp[0], b = mp[1];
    mb = (unsigned)((a.x != 0) | ((a.y != 0) << 1) | ((a.z != 0) << 2) |
                    ((a.w != 0) << 3) | ((b.x != 0) << 4) | ((b.y != 0) << 5) |
                    ((b.z != 0) << 6) | ((b.w != 0) << 7));
    cnt = __popc(mb);
  }
  int incl = cnt;
#pragma unroll
  for (int off = 1; off < 64; off <<= 1) {
    int v = __shfl_up(incl, off);
    if ((tid & 63) >= off) incl += v;
  }
  __shared__ int wsum[4];
  if ((tid & 63) == 63) wsum[tid >> 6] = incl;
  __syncthreads();
  int w = tid >> 6;
  int wo = 0;
  if (w > 0) wo += wsum[0];
  if (w > 1) wo += wsum[1];
  if (w > 2) wo += wsum[2];
  int pos = boff[blockIdx.x] + wo + (incl - cnt);
  if (valid) rowinfo[row] = (pos << 8) | (int)mb;
}

// ---------------------------------------------------------------------------
// Kernel 4: both MLP layers on MFMA + ordered scatter via rowinfo.
// IDENTICAL math to round-10; re-gridded to 512-thread blocks so the same
// 34 KB LDS hosts 8 waves -> 24 waves/CU (was 16 ceiling / ~10 measured).
// Latency-bound theory: TLP x2.4 is the single variable this round.
// ---------------------------------------------------------------------------
__global__ __launch_bounds__(MLP_THREADS, 4) void mlp_kernel(
    const float* __restrict__ x, const float* __restrict__ w0,
    const float* __restrict__ b0, const float* __restrict__ w1,
    const float* __restrict__ b1, const int* __restrict__ rowinfo,
    float* __restrict__ out) {
  __shared__ __bf16 sA[32 * 64 * 8];   // 32 frags x 64 lanes x 8 bf16 = 32 KB
  __shared__ float sB0[512];           // b0 verbatim (frag-sliced reads)

  int tid = threadIdx.x;

  // ---- prologue: stage W0^T fragments (bf16) + b0 ----
#pragma unroll
  for (int i = 0; i < 4; ++i) {
    int fi = i * MLP_THREADS + tid;  // 0..2047
    int frag = fi >> 6;              // hidden-block 0..31 (label = frag*16+m)
    int lane = fi & 63;
    int d = frag >> 2, qb = frag & 3;
    int q = qb * 16 + (lane & 15);   // within-head hidden index
    int kb = (lane >> 4) * 8;        // k chunk per 16-lane group
    bf16x8 v;
#pragma unroll
    for (int j = 0; j < 8; ++j)
      v[j] = (__bf16)w0[d * 2048 + (kb + j) * 64 + q];
    *(bf16x8*)&sA[fi * 8] = v;
  }
  if (tid < 128) *(float4*)&sB0[tid * 4] = *(const float4*)&b0[tid * 4];
  __syncthreads();

  int l = tid & 63;
  int n = l & 15;          // MFMA col / row-in-tile; also A2 row index m
  int g = l >> 4;          // 16-lane group

  // ---- persistent per-lane w1 fragments (labels c1=2n even / 2n+1 odd) ----
  bf16x8 w1A, w1B;
  bool ownrow = (n < 8);
#pragma unroll
  for (int j = 0; j < 8; ++j) {
    int off = (j >> 2) * 16 + g * 4 + (j & 3);
    w1A[j] = ownrow ? (__bf16)w1[n * 64 + off]      : (__bf16)0.f;
    w1B[j] = ownrow ? (__bf16)w1[n * 64 + 32 + off] : (__bf16)0.f;
  }
  int4 w1Ai = *(int4*)&w1A;
  int4 w1Bi = *(int4*)&w1B;
  f32x4 b1C;
#pragma unroll
  for (int r = 0; r < 4; ++r) b1C[r] = b1[(g * 4 + r) & 7];

  int w = tid >> 6;                    // wave 0..7
  int wv = blockIdx.x * 8 + w;
  const int W = MLP_BLOCKS * 8;        // 6144 waves

  for (int b = wv; b < NBATCH; b += W) {
    int t0 = b * TPB;

    // ---- x fragments: B[k][n], k-slot (g,j) -> feature g*8+j ----
    bf16x8 xf0, xf1, xf2, xf3;
    {
      const float* xp;
      float4 a, c;
      uint4 ui;
#define LOADX(T, DST)                                              \
      xp = x + (long)((t0 + T) * 16 + n) * 32 + g * 8;             \
      a = *(const float4*)xp; c = *(const float4*)(xp + 4);        \
      ui.x = cvt_pk_bf16(a.x, a.y); ui.y = cvt_pk_bf16(a.z, a.w); \
      ui.z = cvt_pk_bf16(c.x, c.y); ui.w = cvt_pk_bf16(c.z, c.w); \
      DST = *(bf16x8*)&ui;
      LOADX(0, xf0) LOADX(1, xf1) LOADX(2, xf2) LOADX(3, xf3)
#undef LOADX
    }

    f32x4 O0 = b1C, O1 = b1C, O2 = b1C, O3 = b1C;

#pragma unroll 1
    for (int cp = 0; cp < 8; ++cp) {   // head cp; c1 = 2cp (w1A), 2cp+1 (w1B)
      bool own = (n == cp);
      int4 z4 = {0, 0, 0, 0};
      int4 A2ai = own ? w1Ai : z4;     // 4 cndmask each
      int4 A2bi = own ? w1Bi : z4;
      bf16x8 A2a = *(bf16x8*)&A2ai;
      bf16x8 A2b = *(bf16x8*)&A2bi;
      int fb = cp * 4;                 // 4 layer-0 frags this head
      bf16x8 Aw0 = *(const bf16x8*)&sA[(fb + 0) * 512 + l * 8];
      bf16x8 Aw1 = *(const bf16x8*)&sA[(fb + 1) * 512 + l * 8];
      bf16x8 Aw2 = *(const bf16x8*)&sA[(fb + 2) * 512 + l * 8];
      bf16x8 Aw3 = *(const bf16x8*)&sA[(fb + 3) * 512 + l * 8];
      f32x4 C0 = *(const f32x4*)&sB0[(fb + 0) * 16 + g * 4];
      f32x4 C1 = *(const f32x4*)&sB0[(fb + 1) * 16 + g * 4];
      f32x4 C2 = *(const f32x4*)&sB0[(fb + 2) * 16 + g * 4];
      f32x4 C3 = *(const f32x4*)&sB0[(fb + 3) * 16 + g * 4];

#define TILE(XF, OD) {                                                        \
      f32x4 Da = __builtin_amdgcn_mfma_f32_16x16x32_bf16(Aw0, XF, C0, 0,0,0); \
      f32x4 Db = __builtin_amdgcn_mfma_f32_16x16x32_bf16(Aw1, XF, C1, 0,0,0); \
      uint4 bu;                                                               \
      bu.x = cvt_pk_bf16(fmaxf(Da[0], 0.f), fmaxf(Da[1], 0.f));               \
      bu.y = cvt_pk_bf16(fmaxf(Da[2], 0.f), fmaxf(Da[3], 0.f));               \
      bu.z = cvt_pk_bf16(fmaxf(Db[0], 0.f), fmaxf(Db[1], 0.f));               \
      bu.w = cvt_pk_bf16(fmaxf(Db[2], 0.f), fmaxf(Db[3], 0.f));               \
      bf16x8 B2 = *(bf16x8*)&bu;                                              \
      OD = __builtin_amdgcn_mfma_f32_16x16x32_bf16(A2a, B2, OD, 0, 0, 0);     \
      f32x4 Dc = __builtin_amdgcn_mfma_f32_16x16x32_bf16(Aw2, XF, C2, 0,0,0); \
      f32x4 Dd = __builtin_amdgcn_mfma_f32_16x16x32_bf16(Aw3, XF, C3, 0,0,0); \
      bu.x = cvt_pk_bf16(fmaxf(Dc[0], 0.f), fmaxf(Dc[1], 0.f));               \
      bu.y = cvt_pk_bf16(fmaxf(Dc[2], 0.f), fmaxf(Dc[3], 0.f));               \
      bu.z = cvt_pk_bf16(fmaxf(Dd[0], 0.f), fmaxf(Dd[1], 0.f));               \
      bu.w = cvt_pk_bf16(fmaxf(Dd[2], 0.f), fmaxf(Dd[3], 0.f));               \
      bf16x8 B3 = *(bf16x8*)&bu;                                              \
      OD = __builtin_amdgcn_mfma_f32_16x16x32_bf16(A2b, B3, OD, 0, 0, 0); }
      TILE(xf0, O0) TILE(xf1, O1) TILE(xf2, O2) TILE(xf3, O3)
#undef TILE
    }

    // ---- epilogue: lanes g<2 hold out[d=g*4+r][n]; ordered scatter ----
    if (g < 2) {
#define EPI(T, OD) {                                                     \
      int row = (t0 + T) * 16 + n;                                       \
      int info = rowinfo[row];                                           \
      unsigned mb = (unsigned)info & 255u;                               \
      int pos = (int)(((unsigned)info) >> 8) +                           \
                (g ? __popc(mb & 0xFu) : 0);                             \
      unsigned nib = (mb >> (g * 4)) & 0xFu;                             \
      if (nib & 1u) { out[pos] = OD[0]; pos++; }                         \
      if (nib & 2u) { out[pos] = OD[1]; pos++; }                         \
      if (nib & 4u) { out[pos] = OD[2]; pos++; }                         \
      if (nib & 8u) { out[pos] = OD[3]; }                                }
      EPI(0, O0) EPI(1, O1) EPI(2, O2) EPI(3, O3)
#undef EPI
    }
  }
}

extern "C" void kernel_launch(void* const* d_in, const int* in_sizes, int n_in,
                              void* d_out, int out_size, void* d_ws, size_t ws_size,
                              hipStream_t stream) {
  const float* x    = (const float*)d_in[0];
  const int*   mask = (const int*)d_in[1];
  const float* w0   = (const float*)d_in[2];
  const float* b0   = (const float*)d_in[3];
  const float* w1   = (const float*)d_in[4];
  const float* b1   = (const float*)d_in[5];
  float* out = (float*)d_out;

  int* bsum    = (int*)d_ws;            // NB ints
  int* boff    = bsum + NB;             // NB ints
  int* rowinfo = boff + NB;             // NROWS ints (~4 MB)

  count_kernel<<<NB, 256, 0, stream>>>(mask, bsum);
  scan_kernel<<<1, 1024, 0, stream>>>(bsum, boff);
  expand_kernel<<<NB, 256, 0, stream>>>(mask, boff, rowinfo);
  mlp_kernel<<<MLP_BLOCKS, MLP_THREADS, 0, stream>>>(x, w0, b0, w1, b1, rowinfo, out);
}